// Round 6
// baseline (103.785 us; speedup 1.0000x reference)
//
#include <hip/hip_runtime.h>

#define NROWS 65536
#define NCAT 16
#define BCAT 32   // blocks per category in k_main

typedef __attribute__((ext_vector_type(8))) short short8v;
typedef __attribute__((ext_vector_type(4))) float float4v;
typedef __attribute__((ext_vector_type(16))) float f32x16;

__constant__ int c_shift[NCAT] = {0,4,6,8,12,16,19,22,24,28,34,36,42,45,48,51};
__constant__ int c_len[NCAT]   = {4,2,2,4,4,3,3,2,4,6,2,6,3,3,3,3};

// ws layout (bytes):
//   sv      @ 0        (128 f32)
//   counts  @ 512      (16 i32)
//   blkcnt  @ 576      (256*16 i32)  -> 16960
//   offs    @ 16960    (256*16 i32)  -> 33344
//   scale   @ 33344    (2048 f32)    -> 41536
//   shiftv  @ 41536    (2048 f32)    -> 49728
//   G       @ 49728    (16384 f32)   -> 115264
//   rowidx  @ 115264   (65536 i32)   -> 377408
//   Gpart   @ 377408   (16 MB)       [k_stats -> k_reduce]
//   Wlb     @ 377408   (512 KB)      [k_wswz AFTER k_reduce reuses dead Gpart]
//   svpart  @ 17154624 (256*128 f32 = 128 KB) -> need 17285696

static inline __device__ unsigned short f2bf(float x) {
  union { float f; unsigned int u; } v; v.f = x;
  unsigned int r = v.u + 0x7fffu + ((v.u >> 16) & 1u);   // RNE
  return (unsigned short)(r >> 16);
}

static inline __device__ float pick6(const float p[6], int s) {
  float r = p[0];
  r = (s == 1) ? p[1] : r;
  r = (s == 2) ? p[2] : r;
  r = (s == 3) ? p[3] : r;
  r = (s == 4) ? p[4] : r;
  r = (s == 5) ? p[5] : r;
  return r;
}

// ---------------------------------------------------------------------------
// K1: MFMA Gram. 256 blocks x 1024 thr (16 waves). Block = 256 rows.
// Wave w -> 32x32 C tile; A/B frags gathered directly from global F.
// PART: non-atomic Gpart + svpart stores (no pre-zeroing needed anywhere).
// ---------------------------------------------------------------------------
template<bool PART>
__global__ __launch_bounds__(1024) void k_stats_m(
    const float* __restrict__ F, const int* __restrict__ lab,
    float* __restrict__ Gdst, float* __restrict__ sv,
    float* __restrict__ svpart, int* __restrict__ blkcnt)
{
  __shared__ int hl[NCAT];
  const int tid = threadIdx.x;
  if (tid < NCAT) hl[tid] = 0;
  __syncthreads();
  const int rowbase = blockIdx.x * 256;
  if (tid < 256) atomicAdd(&hl[lab[rowbase + tid]], 1);

  const int wid = tid >> 6, lane = tid & 63;
  const int wi = wid >> 2, wj = wid & 3;
  const int i0 = wi * 32, j0 = wj * 32;
  const int lr = lane & 31, lh = lane >> 5;

  f32x16 acc;
  #pragma unroll
  for (int e = 0; e < 16; ++e) acc[e] = 0.f;
  float svacc = 0.f;

  for (int ch = 0; ch < 8; ++ch) {
    #pragma unroll
    for (int h = 0; h < 2; ++h) {
      const int rbase = rowbase + ch * 32 + 16 * h + 8 * lh;
      float fa[8], fb[8];
      #pragma unroll
      for (int j = 0; j < 8; ++j) {
        const float* rp = F + (size_t)(rbase + j) * 128;
        fa[j] = rp[i0 + lr];
        fb[j] = rp[j0 + lr];
      }
      if (wj == 0) {
        #pragma unroll
        for (int j = 0; j < 8; ++j) svacc += fa[j];
      }
      short8v av, bv;
      #pragma unroll
      for (int j = 0; j < 8; ++j) {
        av[j] = (short)f2bf(fa[j]);
        bv[j] = (short)f2bf(fb[j]);
      }
      acc = __builtin_amdgcn_mfma_f32_32x32x16_bf16(av, bv, acc, 0, 0, 0);
    }
  }

  if (wj == 0) {
    svacc += __shfl_xor(svacc, 32);
    if (lane < 32) {
      if (PART) svpart[blockIdx.x * 128 + i0 + lr] = svacc;
      else      atomicAdd(&sv[i0 + lr], svacc);
    }
  }
  __syncthreads();
  if (tid < NCAT) blkcnt[blockIdx.x * NCAT + tid] = hl[tid];

  if (PART) {
    float* gp = Gdst + (size_t)blockIdx.x * 16384;
    #pragma unroll
    for (int reg = 0; reg < 16; ++reg) {
      const int row = (reg & 3) + 8 * (reg >> 2) + 4 * lh;
      gp[(i0 + row) * 128 + j0 + lr] = acc[reg];
    }
  } else {
    #pragma unroll
    for (int reg = 0; reg < 16; ++reg) {
      const int row = (reg & 3) + 8 * (reg >> 2) + 4 * lh;
      atomicAdd(&Gdst[(i0 + row) * 128 + j0 + lr], acc[reg]);
    }
  }
}

// K1b: reduce 256 partials -> G (16384 elems) and sv (128 elems). grid 258x64.
__global__ __launch_bounds__(64) void k_reduce(
    const float* __restrict__ Gpart, const float* __restrict__ svpart,
    float* __restrict__ G, float* __restrict__ sv)
{
  const int e = blockIdx.x * 64 + threadIdx.x;
  if (e < 16384) {
    float s = 0.f;
    #pragma unroll 8
    for (int p = 0; p < 256; ++p) s += Gpart[(size_t)p * 16384 + e];
    G[e] = s;
  } else if (e < 16512) {
    const int i = e - 16384;
    float s = 0.f;
    #pragma unroll 8
    for (int p = 0; p < 256; ++p) s += svpart[p * 128 + i];
    sv[i] = s;
  }
}

// ---------------------------------------------------------------------------
// K1w: pre-swizzle W1 into bf16 MFMA B-fragment layout.
// ---------------------------------------------------------------------------
__global__ __launch_bounds__(256) void k_wswz(
    const float* __restrict__ W1, unsigned short* __restrict__ Wlb)
{
  const int cat = blockIdx.x >> 2, part = blockIdx.x & 3;
  for (int i = 0; i < 2; ++i) {
    const int e = part * 512 + threadIdx.x + i * 256;
    const int fid = e >> 6, l = e & 63;
    const int ks = fid >> 3, ct = fid & 7;
    const int kb = 32 * ks + 8 * (l >> 4);
    const int c = cat * 128 + 16 * ct + (l & 15);
    unsigned short v[8];
    #pragma unroll
    for (int j = 0; j < 8; ++j)
      v[j] = f2bf(W1[(size_t)(kb + j) * 2048 + c]);
    uint4 pk;
    pk.x = (unsigned)v[0] | ((unsigned)v[1] << 16);
    pk.y = (unsigned)v[2] | ((unsigned)v[3] << 16);
    pk.z = (unsigned)v[4] | ((unsigned)v[5] << 16);
    pk.w = (unsigned)v[6] | ((unsigned)v[7] << 16);
    *(uint4*)(Wlb + ((size_t)(cat * 32 + fid) * 64 + l) * 8) = pk;
  }
}

// ---------------------------------------------------------------------------
// K1c: prefix sums over blkcnt -> offs[block][cat], counts[cat]. 1 block.
// ---------------------------------------------------------------------------
__global__ __launch_bounds__(256) void k_prefix(
    const int* __restrict__ blkcnt, int* __restrict__ offs,
    int* __restrict__ counts)
{
  __shared__ int ps[16][16];
  __shared__ int ps2[16][16];
  __shared__ int tot[16];
  __shared__ int catbase[16];
  const int tid = threadIdx.x;
  const int part = tid >> 4, cat = tid & 15;
  int v[16];
  int s = 0;
  #pragma unroll
  for (int i = 0; i < 16; ++i) {
    v[i] = s;
    s += blkcnt[(part * 16 + i) * 16 + cat];
  }
  ps[part][cat] = s;
  __syncthreads();
  if (part == 0) {
    int acc = 0;
    #pragma unroll
    for (int p = 0; p < 16; ++p) { ps2[p][cat] = acc; acc += ps[p][cat]; }
    tot[cat] = acc;
    counts[cat] = acc;
  }
  __syncthreads();
  if (tid == 0) {
    int acc = 0;
    #pragma unroll
    for (int c = 0; c < 16; ++c) { catbase[c] = acc; acc += tot[c]; }
  }
  __syncthreads();
  const int base = catbase[cat] + ps2[part][cat];
  #pragma unroll
  for (int i = 0; i < 16; ++i)
    offs[(part * 16 + i) * 16 + cat] = base + v[i];
}

// ---------------------------------------------------------------------------
// K3: compact row indices by category — atomic-free, deterministic.
// ---------------------------------------------------------------------------
__global__ __launch_bounds__(256) void k_scatter(
    const int* __restrict__ lab, const int* __restrict__ offs,
    int* __restrict__ rowidx)
{
  __shared__ int wc[4][NCAT];
  const int tid = threadIdx.x;
  const int wid = tid >> 6, lane = tid & 63;
  const int n = blockIdx.x * 256 + tid;
  const int c = lab[n];
  const unsigned long long lanebit = 1ull << lane;
  int myrank = 0;
  #pragma unroll
  for (int cc = 0; cc < NCAT; ++cc) {
    unsigned long long m = __ballot(c == cc);
    if (lane == 0) wc[wid][cc] = (int)__popcll(m);
    if (c == cc) myrank = (int)__popcll(m & (lanebit - 1));
  }
  __syncthreads();
  int base = 0;
  #pragma unroll
  for (int w = 0; w < 4; ++w)
    if (w < wid) base += wc[w][c];
  rowidx[offs[blockIdx.x * NCAT + c] + base + myrank] = n;
}

// ---------------------------------------------------------------------------
// K2: BN parameters from Gram matrix.
// ---------------------------------------------------------------------------
__global__ __launch_bounds__(256) void k_params(
    const float* __restrict__ G, const float* __restrict__ sv,
    const float* __restrict__ W1, const float* __restrict__ gamma,
    const float* __restrict__ beta, float* __restrict__ scale,
    float* __restrict__ shiftv)
{
  __shared__ float Gl[128][133];
  __shared__ float Wl[128][16];
  __shared__ float redq[16][16];
  __shared__ float redm[16][16];
  const int tid = threadIdx.x;
  const int jb = blockIdx.x * 16;
  for (int i = tid; i < 16384; i += 256) Gl[i >> 7][i & 127] = G[i];
  for (int i = tid; i < 2048; i += 256) {
    int k = i >> 4, col = i & 15;
    Wl[k][col] = W1[(size_t)k * 2048 + jb + col];
  }
  __syncthreads();
  const int col = tid & 15, part = tid >> 4;
  float msq = 0.f, mean = 0.f;
  for (int ii = 0; ii < 8; ++ii) {
    const int i = part * 8 + ii;
    const float wi = Wl[i][col];
    float inner = 0.f;
    #pragma unroll 8
    for (int k = 0; k < 128; ++k) inner = fmaf(Gl[i][k], Wl[k][col], inner);
    msq = fmaf(wi, inner, msq);
  }
  #pragma unroll
  for (int kk = 0; kk < 8; ++kk) {
    const int k = part * 8 + kk;
    mean = fmaf(sv[k], Wl[k][col], mean);
  }
  redq[part][col] = msq;
  redm[part][col] = mean;
  __syncthreads();
  if (tid < 16) {
    float q = 0.f, m = 0.f;
    #pragma unroll
    for (int p = 0; p < 16; ++p) { q += redq[p][tid]; m += redm[p][tid]; }
    m *= (1.f / 65536.f);
    q *= (1.f / 65536.f);
    float var = q - m * m;
    float sc = gamma[jb + tid] * rsqrtf(var + 1e-5f);
    scale[jb + tid] = sc;
    shiftv[jb + tid] = beta[jb + tid] - m * sc;
  }
}

// ---------------------------------------------------------------------------
// K4: MFMA main pass. grid = 16 cat x BCAT(32); 512 blocks (all co-resident);
// 4 waves x 16 rows/iter, ~2 iters/block with software prefetch of next
// iteration's rowidx + F data. Writes the FULL 54-col output row (no d_out
// memset): 4 sb-lanes per row write disjoint float2 ranges; in-segment slots
// via select chain.
// ---------------------------------------------------------------------------
__global__ __launch_bounds__(256, 2) void k_main(
    const float* __restrict__ F, const unsigned short* __restrict__ Wlb,
    const float* __restrict__ W2, const float* __restrict__ bias,
    const float* __restrict__ scale, const float* __restrict__ shiftv,
    const int* __restrict__ counts, const int* __restrict__ rowidx,
    float* __restrict__ out)
{
  __shared__ float W2l[768];
  const int tid = threadIdx.x;
  const int cat = (int)blockIdx.x >> 5;
  const int blk = (int)blockIdx.x & (BCAT - 1);
  int off = 0, cnt = 0;
  #pragma unroll
  for (int t = 0; t < NCAT; ++t) {
    int cv = counts[t];
    if (t < cat) off += cv;
    if (t == cat) cnt = cv;
  }
  for (int i = tid; i < 768; i += 256) W2l[i] = W2[cat * 768 + i];
  const int wid = tid >> 6, lane = tid & 63;
  const int lrow = lane & 15, lhi = lane >> 4;
  const int shc = c_shift[cat], lnc = c_len[cat];
  const int f_lo = shc >> 1, f_hi = (shc + lnc - 1) >> 1;
  float bi[6];
  #pragma unroll
  for (int s = 0; s < 6; ++s) bi[s] = bias[s];
  float sc_r[8], sh_r[8];
  #pragma unroll
  for (int ct = 0; ct < 8; ++ct) {
    sc_r[ct] = scale[cat * 128 + ct * 16 + lrow];
    sh_r[ct] = shiftv[cat * 128 + ct * 16 + lrow];
  }
  __syncthreads();

  const unsigned short* wbase = Wlb + (size_t)cat * 16384;
  const int chunk = (cnt + BCAT - 1) / BCAT;
  const int start = off + blk * chunk;
  const int end = min(start + chunk, off + cnt);
  if (start >= end) return;

  float4 cA[4], cB[4];
  {
    const int rA = rowidx[min(start + wid * 16 + lrow, end - 1)];
    const float* fp = F + (size_t)rA * 128 + lhi * 8;
    #pragma unroll
    for (int ks = 0; ks < 4; ++ks) {
      cA[ks] = *(const float4*)(fp + ks * 32);
      cB[ks] = *(const float4*)(fp + ks * 32 + 4);
    }
  }

  for (int q0 = start; q0 < end; q0 += 64) {
    const int qn = q0 + 64;
    const bool hn = qn < end;          // block-uniform
    float4 nA[4], nB[4];
    if (hn) {
      const int rAn = rowidx[min(qn + wid * 16 + lrow, end - 1)];
      const float* fpn = F + (size_t)rAn * 128 + lhi * 8;
      #pragma unroll
      for (int ks = 0; ks < 4; ++ks) {
        nA[ks] = *(const float4*)(fpn + ks * 32);
        nB[ks] = *(const float4*)(fpn + ks * 32 + 4);
      }
    }

    const int base = q0 + wid * 16;
    float4v acc[8];
    #pragma unroll
    for (int ct = 0; ct < 8; ++ct) acc[ct] = (float4v){0.f, 0.f, 0.f, 0.f};

    #pragma unroll
    for (int ks = 0; ks < 4; ++ks) {
      short8v av;
      av[0] = (short)f2bf(cA[ks].x); av[1] = (short)f2bf(cA[ks].y);
      av[2] = (short)f2bf(cA[ks].z); av[3] = (short)f2bf(cA[ks].w);
      av[4] = (short)f2bf(cB[ks].x); av[5] = (short)f2bf(cB[ks].y);
      av[6] = (short)f2bf(cB[ks].z); av[7] = (short)f2bf(cB[ks].w);
      #pragma unroll
      for (int ct = 0; ct < 8; ++ct) {
        short8v bv = *(const short8v*)(wbase + ((ks * 8 + ct) * 64 + lane) * 8);
        acc[ct] = __builtin_amdgcn_mfma_f32_16x16x32_bf16(av, bv, acc[ct], 0, 0, 0);
      }
    }

    // BN + leaky + W2 partials (lane col c = 16ct+lrow; rows 4*lhi+j)
    float p[4][6];
    #pragma unroll
    for (int j = 0; j < 4; ++j)
      #pragma unroll
      for (int s = 0; s < 6; ++s) p[j][s] = 0.f;
    #pragma unroll
    for (int ct = 0; ct < 8; ++ct) {
      const int c = ct * 16 + lrow;
      const float s_ = sc_r[ct], h_ = sh_r[ct];
      float w2v[6];
      #pragma unroll
      for (int s = 0; s < 6; ++s) w2v[s] = W2l[c * 6 + s];
      #pragma unroll
      for (int j = 0; j < 4; ++j) {
        float a = acc[ct][j] * s_ + h_;
        a = (a >= 0.f) ? a : 0.2f * a;
        #pragma unroll
        for (int s = 0; s < 6; ++s) p[j][s] = fmaf(a, w2v[s], p[j][s]);
      }
    }
    // reduce-scatter over the 16-lane group: lvl1/2 keep j == lrow&3
    const bool b1 = (lrow & 1) != 0;
    const bool b2 = (lrow & 2) != 0;
    float q[2][6], r[6];
    #pragma unroll
    for (int t = 0; t < 2; ++t)
      #pragma unroll
      for (int s = 0; s < 6; ++s) {
        float snd = b1 ? p[2 * t][s] : p[2 * t + 1][s];
        float kp  = b1 ? p[2 * t + 1][s] : p[2 * t][s];
        q[t][s] = kp + __shfl_xor(snd, 1);
      }
    #pragma unroll
    for (int s = 0; s < 6; ++s) {
      float snd = b2 ? q[0][s] : q[1][s];
      float kp  = b2 ? q[1][s] : q[0][s];
      r[s] = kp + __shfl_xor(snd, 2);
    }
    #pragma unroll
    for (int s = 0; s < 6; ++s) r[s] += __shfl_xor(r[s], 4);
    #pragma unroll
    for (int s = 0; s < 6; ++s) r[s] += __shfl_xor(r[s], 8);

    const int jj = lrow & 3, sb = lrow >> 2;
    const int rG = rowidx[min(base + 4 * lhi + jj, end - 1)];
    float pj[6];
    #pragma unroll
    for (int s = 0; s < 6; ++s) pj[s] = r[s] + bi[s];
    float mx = fmaxf(fmaxf(fmaxf(pj[0], pj[1]), fmaxf(pj[2], pj[3])), fmaxf(pj[4], pj[5]));
    float e = __expf(pj[0] - mx) + __expf(pj[1] - mx) + __expf(pj[2] - mx)
            + __expf(pj[3] - mx) + __expf(pj[4] - mx) + __expf(pj[5] - mx);
    float lse = mx + __logf(e);

    // full-row store: lane sb owns float2 indices sb*7 .. sb*7+6 (27 total)
    float2* orow = (float2*)(out + (size_t)rG * 54);
    #pragma unroll
    for (int t = 0; t < 7; ++t) {
      const int c2 = sb * 7 + t;
      if (c2 < 27) {
        float2 v; v.x = 0.f; v.y = 0.f;
        if (c2 >= f_lo && c2 <= f_hi) {
          const int s0 = c2 * 2 - shc, s1 = s0 + 1;
          if (s0 >= 0 && s0 < lnc) v.x = pick6(pj, s0) - lse;
          if (s1 >= 0 && s1 < lnc) v.y = pick6(pj, s1) - lse;
        }
        orow[c2] = v;
      }
    }

    if (hn) {
      #pragma unroll
      for (int ks = 0; ks < 4; ++ks) { cA[ks] = nA[ks]; cB[ks] = nB[ks]; }
    }
  }
}

// ---------------------------------------------------------------------------
// Host launcher
// ---------------------------------------------------------------------------
extern "C" void kernel_launch(void* const* d_in, const int* in_sizes, int n_in,
                              void* d_out, int out_size, void* d_ws, size_t ws_size,
                              hipStream_t stream) {
  const float* F     = (const float*)d_in[0];
  const float* W1    = (const float*)d_in[1];
  const float* gamma = (const float*)d_in[2];
  const float* beta  = (const float*)d_in[3];
  const float* W2    = (const float*)d_in[4];
  const float* bias  = (const float*)d_in[5];
  const int*   lab   = (const int*)d_in[6];
  float* out = (float*)d_out;

  char* ws = (char*)d_ws;
  float* sv      = (float*)(ws + 0);
  int*   counts  = (int*)(ws + 512);
  int*   blkcnt  = (int*)(ws + 576);
  int*   offs    = (int*)(ws + 16960);
  float* scale   = (float*)(ws + 33344);
  float* shiftv  = (float*)(ws + 41536);
  float* G       = (float*)(ws + 49728);
  int*   rowidx  = (int*)(ws + 115264);
  float* Gpart   = (float*)(ws + 377408);
  unsigned short* Wlb = (unsigned short*)(ws + 377408);  // reuses Gpart after k_reduce
  float* svpart  = (float*)(ws + 17154624);

  const size_t need = 17154624 + 131072;  // ~17.3 MB
  if (ws_size >= need) {
    // fast path: zero fill dispatches — all reductions are non-atomic
    hipLaunchKernelGGL(k_stats_m<true>, dim3(256), dim3(1024), 0, stream,
                       F, lab, Gpart, sv, svpart, blkcnt);
    hipLaunchKernelGGL(k_reduce, dim3(258), dim3(64), 0, stream, Gpart, svpart, G, sv);
  } else {
    hipMemsetAsync(d_ws, 0, 115264, stream); // sv + G for atomics
    hipLaunchKernelGGL(k_stats_m<false>, dim3(256), dim3(1024), 0, stream,
                       F, lab, G, sv, svpart, blkcnt);
  }
  hipLaunchKernelGGL(k_wswz, dim3(64), dim3(256), 0, stream, W1, Wlb);
  hipLaunchKernelGGL(k_prefix, dim3(1), dim3(256), 0, stream, blkcnt, offs, counts);
  hipLaunchKernelGGL(k_scatter, dim3(256), dim3(256), 0, stream, lab, offs, rowidx);
  hipLaunchKernelGGL(k_params, dim3(128), dim3(256), 0, stream, G, sv, W1, gamma, beta, scale, shiftv);
  hipLaunchKernelGGL(k_main, dim3(NCAT * BCAT), dim3(256), 0, stream, F, Wlb, W2, bias,
                     scale, shiftv, counts, rowidx, out);
}

// Round 7
// 92.257 us; speedup vs baseline: 1.1249x; 1.1249x over previous
//
#include <hip/hip_runtime.h>
#include <hip/hip_bf16.h>

#define NCAT 16
#define BCAT 32   // blocks per category in k_main

typedef __attribute__((ext_vector_type(8))) short short8v;
typedef __attribute__((ext_vector_type(4))) float float4v;
typedef __attribute__((ext_vector_type(16))) float f32x16;

__constant__ int c_shift[NCAT] = {0,4,6,8,12,16,19,22,24,28,34,36,42,45,48,51};
__constant__ int c_len[NCAT]   = {4,2,2,4,4,3,3,2,4,6,2,6,3,3,3,3};

// ws layout (bytes):
//   sv      @ 0        (128 f32)
//   counts  @ 512      (16 i32)
//   blkcnt  @ 576      (256*16 i32)  -> 16960
//   offs    @ 16960    (256*16 i32)  -> 33344
//   scale   @ 33344    (2048 f32)    -> 41536
//   shiftv  @ 41536    (2048 f32)    -> 49728
//   G       @ 49728    (16384 f32)   -> 115264
//   rowidx  @ 115264   (65536 i32)   -> 377408
//   posidx  @ 377408   (65536 i32)   -> 639552
//   Wlb     @ 639552   (512 KB)      -> 1163840
//   tmp8    @ 1163840  (65536*8 f32 = 2 MB) -> 3260992   [k_main -> k_out]
//   Gp16    @ 3260992  (256*8192 u32 = 8 MB) -> 11649600 [dead after k_mid]
//   svpart  @ 11649600 (256*128 f32 = 128 KB) -> 11780672   need ~11.8 MB

static inline __device__ unsigned pk2(float lo, float hi) {
  float2 f2; f2.x = lo; f2.y = hi;
  __hip_bfloat162 h = __float22bfloat162_rn(f2);
  unsigned u; __builtin_memcpy(&u, &h, 4);
  return u;
}
static inline __device__ float bf2f(unsigned short v) {
  unsigned u = (unsigned)v << 16;
  float f; __builtin_memcpy(&f, &u, 4);
  return f;
}
static inline __device__ float pick6(const float p[6], int s) {
  float r = p[0];
  r = (s == 1) ? p[1] : r;
  r = (s == 2) ? p[2] : r;
  r = (s == 3) ? p[3] : r;
  r = (s == 4) ? p[4] : r;
  r = (s == 5) ? p[5] : r;
  return r;
}

// ---------------------------------------------------------------------------
// K1: MFMA Gram. 256 blocks x 1024 thr (16 waves). Block = 256 rows.
// Wave (wi,wj) -> 32x32 C tile; A/B frags coalesced 128B segments from F.
// PART: bf16-packed per-block partials (row pairs) + svpart, non-atomic.
// ---------------------------------------------------------------------------
template<bool PART>
__global__ __launch_bounds__(1024) void k_stats_m(
    const float* __restrict__ F, const int* __restrict__ lab,
    float* __restrict__ Gdst, unsigned* __restrict__ Gp16,
    float* __restrict__ sv, float* __restrict__ svpart,
    int* __restrict__ blkcnt)
{
  __shared__ int hl[NCAT];
  const int tid = threadIdx.x;
  if (tid < NCAT) hl[tid] = 0;
  __syncthreads();
  const int rowbase = blockIdx.x * 256;
  if (tid < 256) atomicAdd(&hl[lab[rowbase + tid]], 1);

  const int wid = tid >> 6, lane = tid & 63;
  const int wi = wid >> 2, wj = wid & 3;
  const int i0 = wi * 32, j0 = wj * 32;
  const int lr = lane & 31, lh = lane >> 5;

  f32x16 acc;
  #pragma unroll
  for (int e = 0; e < 16; ++e) acc[e] = 0.f;
  float svacc = 0.f;

  for (int ch = 0; ch < 8; ++ch) {
    #pragma unroll
    for (int h = 0; h < 2; ++h) {
      const int rbase = rowbase + ch * 32 + 16 * h + 8 * lh;
      float fa[8], fb[8];
      #pragma unroll
      for (int j = 0; j < 8; ++j) {
        const float* rp = F + (size_t)(rbase + j) * 128;
        fa[j] = rp[i0 + lr];
        fb[j] = rp[j0 + lr];
      }
      if (wj == 0) {
        #pragma unroll
        for (int j = 0; j < 8; ++j) svacc += fa[j];
      }
      uint4 av4, bv4;
      av4.x = pk2(fa[0], fa[1]); av4.y = pk2(fa[2], fa[3]);
      av4.z = pk2(fa[4], fa[5]); av4.w = pk2(fa[6], fa[7]);
      bv4.x = pk2(fb[0], fb[1]); bv4.y = pk2(fb[2], fb[3]);
      bv4.z = pk2(fb[4], fb[5]); bv4.w = pk2(fb[6], fb[7]);
      acc = __builtin_amdgcn_mfma_f32_32x32x16_bf16(
          __builtin_bit_cast(short8v, av4), __builtin_bit_cast(short8v, bv4),
          acc, 0, 0, 0);
    }
  }

  if (wj == 0) {
    svacc += __shfl_xor(svacc, 32);
    if (lane < 32) {
      if (PART) svpart[blockIdx.x * 128 + i0 + lr] = svacc;
      else      atomicAdd(&sv[i0 + lr], svacc);
    }
  }
  __syncthreads();
  if (tid < NCAT) blkcnt[blockIdx.x * NCAT + tid] = hl[tid];

  if (PART) {
    unsigned* gp = Gp16 + (size_t)blockIdx.x * 8192;
    #pragma unroll
    for (int t = 0; t < 8; ++t) {
      // reg pair (2t, 2t+1) -> rows (rowe, rowe+1), same col
      const int rowe = ((2 * t) & 3) + 8 * (t >> 1) + 4 * lh;
      gp[((i0 + rowe) >> 1) * 128 + j0 + lr] = pk2(acc[2 * t], acc[2 * t + 1]);
    }
  } else {
    #pragma unroll
    for (int reg = 0; reg < 16; ++reg) {
      const int row = (reg & 3) + 8 * (reg >> 2) + 4 * lh;
      atomicAdd(&Gdst[(i0 + row) * 128 + j0 + lr], acc[reg]);
    }
  }
}

// ---------------------------------------------------------------------------
// K2 (fused): b<32 G-reduce (bf16 pairs); b==32 sv-reduce; 33<=b<49 W-swizzle
// (cat = b-33); b==49 prefix sums. grid 50 x 256.
// ---------------------------------------------------------------------------
__global__ __launch_bounds__(256) void k_mid(
    const unsigned* __restrict__ Gp16, const float* __restrict__ svpart,
    const float* __restrict__ W1, const int* __restrict__ blkcnt,
    float* __restrict__ G, float* __restrict__ sv,
    unsigned short* __restrict__ Wlb, int* __restrict__ offs,
    int* __restrict__ counts, int doRed)
{
  __shared__ int ps[16][16], ps2[16][16], tot[16], catbase[16];
  const int b = blockIdx.x, tid = threadIdx.x;
  if (b < 32) {
    if (!doRed) return;
    const int e = b * 256 + tid;           // pair index 0..8191
    float lo = 0.f, hi = 0.f;
    #pragma unroll 4
    for (int p = 0; p < 256; ++p) {
      const unsigned u = Gp16[(size_t)p * 8192 + e];
      lo += bf2f((unsigned short)(u & 0xffffu));
      hi += bf2f((unsigned short)(u >> 16));
    }
    const int pr = e >> 7, col = e & 127;
    G[(2 * pr) * 128 + col]     = lo;
    G[(2 * pr + 1) * 128 + col] = hi;
  } else if (b == 32) {
    if (!doRed) return;
    if (tid < 128) {
      float s = 0.f;
      #pragma unroll 8
      for (int p = 0; p < 256; ++p) s += svpart[p * 128 + tid];
      sv[tid] = s;
    }
  } else if (b < 49) {
    const int cat = b - 33;
    for (int e = tid; e < 2048; e += 256) {
      const int fid = e >> 6, l = e & 63;
      const int ks = fid >> 3, ct = fid & 7;
      const int kb = 32 * ks + 8 * (l >> 4);
      const int c = cat * 128 + 16 * ct + (l & 15);
      uint4 pk;
      pk.x = pk2(W1[(size_t)(kb + 0) * 2048 + c], W1[(size_t)(kb + 1) * 2048 + c]);
      pk.y = pk2(W1[(size_t)(kb + 2) * 2048 + c], W1[(size_t)(kb + 3) * 2048 + c]);
      pk.z = pk2(W1[(size_t)(kb + 4) * 2048 + c], W1[(size_t)(kb + 5) * 2048 + c]);
      pk.w = pk2(W1[(size_t)(kb + 6) * 2048 + c], W1[(size_t)(kb + 7) * 2048 + c]);
      *(uint4*)(Wlb + ((size_t)(cat * 32 + fid) * 64 + l) * 8) = pk;
    }
  } else {
    const int part = tid >> 4, cat = tid & 15;
    int v[16]; int s = 0;
    #pragma unroll
    for (int i = 0; i < 16; ++i) { v[i] = s; s += blkcnt[(part * 16 + i) * 16 + cat]; }
    ps[part][cat] = s;
    __syncthreads();
    if (part == 0) {
      int a = 0;
      #pragma unroll
      for (int p = 0; p < 16; ++p) { ps2[p][cat] = a; a += ps[p][cat]; }
      tot[cat] = a; counts[cat] = a;
    }
    __syncthreads();
    if (tid == 0) {
      int a = 0;
      #pragma unroll
      for (int c = 0; c < 16; ++c) { catbase[c] = a; a += tot[c]; }
    }
    __syncthreads();
    const int base = catbase[cat] + ps2[part][cat];
    #pragma unroll
    for (int i = 0; i < 16; ++i) offs[(part * 16 + i) * 16 + cat] = base + v[i];
  }
}

// ---------------------------------------------------------------------------
// K3 (fused): b<256 scatter (rowidx + posidx, atomic-free); b>=256 BN params
// (jb = (b-256)*16, tid<256 active). grid 384 x 256.
// ---------------------------------------------------------------------------
__global__ __launch_bounds__(256) void k_prep(
    const int* __restrict__ lab, const int* __restrict__ offs,
    const float* __restrict__ G, const float* __restrict__ sv,
    const float* __restrict__ W1, const float* __restrict__ gamma,
    const float* __restrict__ beta,
    int* __restrict__ rowidx, int* __restrict__ posidx,
    float* __restrict__ scale, float* __restrict__ shiftv)
{
  __shared__ float Gl[128][133];
  __shared__ float Wl[128][16];
  __shared__ float redq[16][16];
  __shared__ float redm[16][16];
  __shared__ int wc[4][NCAT];
  const int b = blockIdx.x, tid = threadIdx.x;
  if (b < 256) {
    const int wid = tid >> 6, lane = tid & 63;
    const int n = b * 256 + tid;
    const int c = lab[n];
    const unsigned long long lanebit = 1ull << lane;
    int myrank = 0;
    #pragma unroll
    for (int cc = 0; cc < NCAT; ++cc) {
      unsigned long long m = __ballot(c == cc);
      if (lane == 0) wc[wid][cc] = (int)__popcll(m);
      if (c == cc) myrank = (int)__popcll(m & (lanebit - 1));
    }
    __syncthreads();
    int base = 0;
    #pragma unroll
    for (int w = 0; w < 4; ++w)
      if (w < wid) base += wc[w][c];
    const int slot = offs[b * NCAT + c] + base + myrank;
    rowidx[slot] = n;
    posidx[n] = slot;
  } else {
    const int jb = (b - 256) * 16;
    for (int i = tid; i < 16384; i += 256) Gl[i >> 7][i & 127] = G[i];
    for (int i = tid; i < 2048; i += 256) {
      int k = i >> 4, col = i & 15;
      Wl[k][col] = W1[(size_t)k * 2048 + jb + col];
    }
    __syncthreads();
    const int col = tid & 15, part = tid >> 4;
    float msq = 0.f, mean = 0.f;
    for (int ii = 0; ii < 8; ++ii) {
      const int i = part * 8 + ii;
      const float wi = Wl[i][col];
      float inner = 0.f;
      #pragma unroll 8
      for (int k = 0; k < 128; ++k) inner = fmaf(Gl[i][k], Wl[k][col], inner);
      msq = fmaf(wi, inner, msq);
    }
    #pragma unroll
    for (int kk = 0; kk < 8; ++kk) {
      const int k = part * 8 + kk;
      mean = fmaf(sv[k], Wl[k][col], mean);
    }
    redq[part][col] = msq;
    redm[part][col] = mean;
    __syncthreads();
    if (tid < 16) {
      float q = 0.f, m = 0.f;
      #pragma unroll
      for (int p = 0; p < 16; ++p) { q += redq[p][tid]; m += redm[p][tid]; }
      m *= (1.f / 65536.f);
      q *= (1.f / 65536.f);
      float var = q - m * m;
      float sc = gamma[jb + tid] * rsqrtf(var + 1e-5f);
      scale[jb + tid] = sc;
      shiftv[jb + tid] = beta[jb + tid] - m * sc;
    }
  }
}

// ---------------------------------------------------------------------------
// K4: MFMA main pass. grid = 16 cat x BCAT(32); 4 waves x 16 rows/iter with
// prefetch. Output: 32-B record per row at its rowidx-SLOT position in tmp8
// (block-contiguous streaming stores -> zero cross-block line sharing).
// ---------------------------------------------------------------------------
__global__ __launch_bounds__(256, 2) void k_main(
    const float* __restrict__ F, const unsigned short* __restrict__ Wlb,
    const float* __restrict__ W2, const float* __restrict__ bias,
    const float* __restrict__ scale, const float* __restrict__ shiftv,
    const int* __restrict__ counts, const int* __restrict__ rowidx,
    float* __restrict__ tmp8)
{
  __shared__ float W2l[768];
  const int tid = threadIdx.x;
  const int cat = (int)blockIdx.x >> 5;
  const int blk = (int)blockIdx.x & (BCAT - 1);
  int off = 0, cnt = 0;
  #pragma unroll
  for (int t = 0; t < NCAT; ++t) {
    int cv = counts[t];
    if (t < cat) off += cv;
    if (t == cat) cnt = cv;
  }
  for (int i = tid; i < 768; i += 256) W2l[i] = W2[cat * 768 + i];
  const int wid = tid >> 6, lane = tid & 63;
  const int lrow = lane & 15, lhi = lane >> 4;
  float bi[6];
  #pragma unroll
  for (int s = 0; s < 6; ++s) bi[s] = bias[s];
  float sc_r[8], sh_r[8];
  #pragma unroll
  for (int ct = 0; ct < 8; ++ct) {
    sc_r[ct] = scale[cat * 128 + ct * 16 + lrow];
    sh_r[ct] = shiftv[cat * 128 + ct * 16 + lrow];
  }
  __syncthreads();

  const unsigned short* wbase = Wlb + (size_t)cat * 16384;
  const int chunk = (cnt + BCAT - 1) / BCAT;
  const int start = off + blk * chunk;
  const int end = min(start + chunk, off + cnt);
  if (start >= end) return;

  float4 cA[4], cB[4];
  {
    const int rA = rowidx[min(start + wid * 16 + lrow, end - 1)];
    const float* fp = F + (size_t)rA * 128 + lhi * 8;
    #pragma unroll
    for (int ks = 0; ks < 4; ++ks) {
      cA[ks] = *(const float4*)(fp + ks * 32);
      cB[ks] = *(const float4*)(fp + ks * 32 + 4);
    }
  }

  for (int q0 = start; q0 < end; q0 += 64) {
    const int qn = q0 + 64;
    const bool hn = qn < end;
    float4 nA[4], nB[4];
    if (hn) {
      const int rAn = rowidx[min(qn + wid * 16 + lrow, end - 1)];
      const float* fpn = F + (size_t)rAn * 128 + lhi * 8;
      #pragma unroll
      for (int ks = 0; ks < 4; ++ks) {
        nA[ks] = *(const float4*)(fpn + ks * 32);
        nB[ks] = *(const float4*)(fpn + ks * 32 + 4);
      }
    }

    const int base = q0 + wid * 16;
    float4v acc[8];
    #pragma unroll
    for (int ct = 0; ct < 8; ++ct) acc[ct] = (float4v){0.f, 0.f, 0.f, 0.f};

    #pragma unroll
    for (int ks = 0; ks < 4; ++ks) {
      uint4 av4;
      av4.x = pk2(cA[ks].x, cA[ks].y); av4.y = pk2(cA[ks].z, cA[ks].w);
      av4.z = pk2(cB[ks].x, cB[ks].y); av4.w = pk2(cB[ks].z, cB[ks].w);
      const short8v av = __builtin_bit_cast(short8v, av4);
      #pragma unroll
      for (int ct = 0; ct < 8; ++ct) {
        short8v bv = *(const short8v*)(wbase + ((ks * 8 + ct) * 64 + lane) * 8);
        acc[ct] = __builtin_amdgcn_mfma_f32_16x16x32_bf16(av, bv, acc[ct], 0, 0, 0);
      }
    }

    // BN + leaky + W2 partials (lane col c = 16ct+lrow; rows 4*lhi+j)
    float p[4][6];
    #pragma unroll
    for (int j = 0; j < 4; ++j)
      #pragma unroll
      for (int s = 0; s < 6; ++s) p[j][s] = 0.f;
    #pragma unroll
    for (int ct = 0; ct < 8; ++ct) {
      const int c = ct * 16 + lrow;
      const float s_ = sc_r[ct], h_ = sh_r[ct];
      float w2v[6];
      #pragma unroll
      for (int s = 0; s < 6; ++s) w2v[s] = W2l[c * 6 + s];
      #pragma unroll
      for (int j = 0; j < 4; ++j) {
        float a = acc[ct][j] * s_ + h_;
        a = (a >= 0.f) ? a : 0.2f * a;
        #pragma unroll
        for (int s = 0; s < 6; ++s) p[j][s] = fmaf(a, w2v[s], p[j][s]);
      }
    }
    // reduce-scatter over the 16-lane group: lvl1/2 keep j == lrow&3
    const bool b1 = (lrow & 1) != 0;
    const bool b2 = (lrow & 2) != 0;
    float q[2][6], r[6];
    #pragma unroll
    for (int t = 0; t < 2; ++t)
      #pragma unroll
      for (int s = 0; s < 6; ++s) {
        float snd = b1 ? p[2 * t][s] : p[2 * t + 1][s];
        float kp  = b1 ? p[2 * t + 1][s] : p[2 * t][s];
        q[t][s] = kp + __shfl_xor(snd, 1);
      }
    #pragma unroll
    for (int s = 0; s < 6; ++s) {
      float snd = b2 ? q[0][s] : q[1][s];
      float kp  = b2 ? q[1][s] : q[0][s];
      r[s] = kp + __shfl_xor(snd, 2);
    }
    #pragma unroll
    for (int s = 0; s < 6; ++s) r[s] += __shfl_xor(r[s], 4);
    #pragma unroll
    for (int s = 0; s < 6; ++s) r[s] += __shfl_xor(r[s], 8);

    const int jj = lrow & 3, sb = lrow >> 2;
    const int qrow = min(base + 4 * lhi + jj, end - 1);  // slot position
    float pj[6];
    #pragma unroll
    for (int s = 0; s < 6; ++s) pj[s] = r[s] + bi[s];
    float mx = fmaxf(fmaxf(fmaxf(pj[0], pj[1]), fmaxf(pj[2], pj[3])), fmaxf(pj[4], pj[5]));
    float e = __expf(pj[0] - mx) + __expf(pj[1] - mx) + __expf(pj[2] - mx)
            + __expf(pj[3] - mx) + __expf(pj[4] - mx) + __expf(pj[5] - mx);
    float lse = mx + __logf(e);

    float4* trec = (float4*)(tmp8 + (size_t)qrow * 8);
    if (sb == 0) {
      float4 v0; v0.x = pj[0] - lse; v0.y = pj[1] - lse;
      v0.z = pj[2] - lse; v0.w = pj[3] - lse;
      trec[0] = v0;
    } else if (sb == 1) {
      float4 v1; v1.x = pj[4] - lse; v1.y = pj[5] - lse;
      v1.z = 0.f; v1.w = 0.f;
      trec[1] = v1;
    }

    if (hn) {
      #pragma unroll
      for (int ks = 0; ks < 4; ++ks) { cA[ks] = nA[ks]; cB[ks] = nB[ks]; }
    }
  }
}

// ---------------------------------------------------------------------------
// K5: permute records -> dense output, writes in OUTPUT order (fully
// coalesced full-line stores, no RMW). grid 6912 x 256 (one float2/thread).
// ---------------------------------------------------------------------------
__global__ __launch_bounds__(256) void k_out(
    const float* __restrict__ tmp8, const int* __restrict__ lab,
    const int* __restrict__ posidx, float* __restrict__ out)
{
  const int i2 = blockIdx.x * 256 + threadIdx.x;  // 0 .. 65536*27
  const int n = i2 / 27;
  const int j2 = i2 - n * 27;
  const int c = lab[n];
  const int shc = c_shift[c], lnc = c_len[c];
  const float* rec = tmp8 + (size_t)posidx[n] * 8;
  const int s0 = 2 * j2 - shc;
  float2 v; v.x = 0.f; v.y = 0.f;
  if (s0 >= 0 && s0 < lnc)         v.x = rec[s0];
  if (s0 + 1 >= 0 && s0 + 1 < lnc) v.y = rec[s0 + 1];
  ((float2*)out)[i2] = v;
}

// ---------------------------------------------------------------------------
// Host launcher
// ---------------------------------------------------------------------------
extern "C" void kernel_launch(void* const* d_in, const int* in_sizes, int n_in,
                              void* d_out, int out_size, void* d_ws, size_t ws_size,
                              hipStream_t stream) {
  const float* F     = (const float*)d_in[0];
  const float* W1    = (const float*)d_in[1];
  const float* gamma = (const float*)d_in[2];
  const float* beta  = (const float*)d_in[3];
  const float* W2    = (const float*)d_in[4];
  const float* bias  = (const float*)d_in[5];
  const int*   lab   = (const int*)d_in[6];
  float* out = (float*)d_out;

  char* ws = (char*)d_ws;
  float* sv      = (float*)(ws + 0);
  int*   counts  = (int*)(ws + 512);
  int*   blkcnt  = (int*)(ws + 576);
  int*   offs    = (int*)(ws + 16960);
  float* scale   = (float*)(ws + 33344);
  float* shiftv  = (float*)(ws + 41536);
  float* G       = (float*)(ws + 49728);
  int*   rowidx  = (int*)(ws + 115264);
  int*   posidx  = (int*)(ws + 377408);
  unsigned short* Wlb = (unsigned short*)(ws + 639552);
  float* tmp8    = (float*)(ws + 1163840);
  unsigned* Gp16 = (unsigned*)(ws + 3260992);
  float* svpart  = (float*)(ws + 11649600);

  const size_t need = 11780672;  // ~11.8 MB (well under proven 17.3 MB)
  const int fast = (ws_size >= need) ? 1 : 0;
  if (fast) {
    hipLaunchKernelGGL(k_stats_m<true>, dim3(256), dim3(1024), 0, stream,
                       F, lab, G, Gp16, sv, svpart, blkcnt);
  } else {
    hipMemsetAsync(d_ws, 0, 115264, stream);  // sv + G for atomic path
    hipLaunchKernelGGL(k_stats_m<false>, dim3(256), dim3(1024), 0, stream,
                       F, lab, G, Gp16, sv, svpart, blkcnt);
  }
  hipLaunchKernelGGL(k_mid, dim3(50), dim3(256), 0, stream,
                     Gp16, svpart, W1, blkcnt, G, sv, Wlb, offs, counts, fast);
  hipLaunchKernelGGL(k_prep, dim3(384), dim3(256), 0, stream,
                     lab, offs, G, sv, W1, gamma, beta, rowidx, posidx, scale, shiftv);
  hipLaunchKernelGGL(k_main, dim3(NCAT * BCAT), dim3(256), 0, stream,
                     F, Wlb, W2, bias, scale, shiftv, counts, rowidx, tmp8);
  hipLaunchKernelGGL(k_out, dim3(6912), dim3(256), 0, stream,
                     tmp8, lab, posidx, out);
}

// Round 8
// 73.927 us; speedup vs baseline: 1.4039x; 1.2480x over previous
//
#include <hip/hip_runtime.h>
#include <hip/hip_bf16.h>

#define NCAT 16

typedef __attribute__((ext_vector_type(8))) short short8v;
typedef __attribute__((ext_vector_type(4))) float float4v;
typedef __attribute__((ext_vector_type(16))) float f32x16;

__constant__ int c_shift[NCAT] = {0,4,6,8,12,16,19,22,24,28,34,36,42,45,48,51};
__constant__ int c_len[NCAT]   = {4,2,2,4,4,3,3,2,4,6,2,6,3,3,3,3};

// ws layout (bytes):
//   scale  @ 0        (2048 f32)  -> 8192
//   shiftv @ 8192     (2048 f32)  -> 16384
//   G      @ 16384    (16384 f32) -> 81920
//   sv     @ 81920    (128 f32)   -> 82432
//   Wlb    @ 82432    (512 KB)    -> 606720
//   Gp16   @ 606720   (8 MB)      -> 8995328
//   svpart @ 8995328  (128 KB)    -> 9126400   need ~9.13 MB

static inline __device__ unsigned pk2(float lo, float hi) {
  float2 f2; f2.x = lo; f2.y = hi;
  __hip_bfloat162 h = __float22bfloat162_rn(f2);
  unsigned u; __builtin_memcpy(&u, &h, 4);
  return u;
}
static inline __device__ float bf2f(unsigned short v) {
  unsigned u = (unsigned)v << 16;
  float f; __builtin_memcpy(&f, &u, 4);
  return f;
}

// ---------------------------------------------------------------------------
// K1: blocks 0..255 = MFMA Gram (256 rows each, 16 waves, 32x32 tiles,
// bf16-packed partials, no atomics, no histogram). Blocks 256..271 = W1
// pre-swizzle into MFMA B-frag layout (one cat per block).
// ---------------------------------------------------------------------------
template<bool PART>
__global__ __launch_bounds__(1024) void k_stats_m(
    const float* __restrict__ F, const float* __restrict__ W1,
    float* __restrict__ Gdst, unsigned* __restrict__ Gp16,
    float* __restrict__ sv, float* __restrict__ svpart,
    unsigned short* __restrict__ Wlb)
{
  const int tid = threadIdx.x;
  if (blockIdx.x >= 256) {
    const int cat = (int)blockIdx.x - 256;
    for (int e = tid; e < 2048; e += 1024) {
      const int fid = e >> 6, l = e & 63;
      const int ks = fid >> 3, ct = fid & 7;
      const int kb = 32 * ks + 8 * (l >> 4);
      const int c = cat * 128 + 16 * ct + (l & 15);
      uint4 pk;
      pk.x = pk2(W1[(size_t)(kb + 0) * 2048 + c], W1[(size_t)(kb + 1) * 2048 + c]);
      pk.y = pk2(W1[(size_t)(kb + 2) * 2048 + c], W1[(size_t)(kb + 3) * 2048 + c]);
      pk.z = pk2(W1[(size_t)(kb + 4) * 2048 + c], W1[(size_t)(kb + 5) * 2048 + c]);
      pk.w = pk2(W1[(size_t)(kb + 6) * 2048 + c], W1[(size_t)(kb + 7) * 2048 + c]);
      *(uint4*)(Wlb + ((size_t)(cat * 32 + fid) * 64 + l) * 8) = pk;
    }
    return;
  }

  const int rowbase = blockIdx.x * 256;
  const int wid = tid >> 6, lane = tid & 63;
  const int wi = wid >> 2, wj = wid & 3;
  const int i0 = wi * 32, j0 = wj * 32;
  const int lr = lane & 31, lh = lane >> 5;

  f32x16 acc;
  #pragma unroll
  for (int e = 0; e < 16; ++e) acc[e] = 0.f;
  float svacc = 0.f;

  for (int ch = 0; ch < 8; ++ch) {
    #pragma unroll
    for (int h = 0; h < 2; ++h) {
      const int rbase = rowbase + ch * 32 + 16 * h + 8 * lh;
      float fa[8], fb[8];
      #pragma unroll
      for (int j = 0; j < 8; ++j) {
        const float* rp = F + (size_t)(rbase + j) * 128;
        fa[j] = rp[i0 + lr];
        fb[j] = rp[j0 + lr];
      }
      if (wj == 0) {
        #pragma unroll
        for (int j = 0; j < 8; ++j) svacc += fa[j];
      }
      uint4 av4, bv4;
      av4.x = pk2(fa[0], fa[1]); av4.y = pk2(fa[2], fa[3]);
      av4.z = pk2(fa[4], fa[5]); av4.w = pk2(fa[6], fa[7]);
      bv4.x = pk2(fb[0], fb[1]); bv4.y = pk2(fb[2], fb[3]);
      bv4.z = pk2(fb[4], fb[5]); bv4.w = pk2(fb[6], fb[7]);
      acc = __builtin_amdgcn_mfma_f32_32x32x16_bf16(
          __builtin_bit_cast(short8v, av4), __builtin_bit_cast(short8v, bv4),
          acc, 0, 0, 0);
    }
  }

  if (wj == 0) {
    svacc += __shfl_xor(svacc, 32);
    if (lane < 32) {
      if (PART) svpart[blockIdx.x * 128 + i0 + lr] = svacc;
      else      atomicAdd(&sv[i0 + lr], svacc);
    }
  }

  if (PART) {
    unsigned* gp = Gp16 + (size_t)blockIdx.x * 8192;
    #pragma unroll
    for (int t = 0; t < 8; ++t) {
      const int rowe = ((2 * t) & 3) + 8 * (t >> 1) + 4 * lh;   // even row of pair
      gp[((i0 + rowe) >> 1) * 128 + j0 + lr] = pk2(acc[2 * t], acc[2 * t + 1]);
    }
  } else {
    #pragma unroll
    for (int reg = 0; reg < 16; ++reg) {
      const int row = (reg & 3) + 8 * (reg >> 2) + 4 * lh;
      atomicAdd(&Gdst[(i0 + row) * 128 + j0 + lr], acc[reg]);
    }
  }
}

// ---------------------------------------------------------------------------
// K2: reduce partials. b<64: G pairs, 2 threads/elem (half-split + shfl);
// b==64: sv. grid 65 x 256.
// ---------------------------------------------------------------------------
__global__ __launch_bounds__(256) void k_reduce(
    const unsigned* __restrict__ Gp16, const float* __restrict__ svpart,
    float* __restrict__ G, float* __restrict__ sv)
{
  const int b = blockIdx.x, tid = threadIdx.x;
  if (b < 64) {
    const int e = b * 128 + (tid >> 1);      // pair index 0..8191
    const int half = tid & 1;
    float lo = 0.f, hi = 0.f;
    #pragma unroll 4
    for (int p = half * 128; p < half * 128 + 128; ++p) {
      const unsigned u = Gp16[(size_t)p * 8192 + e];
      lo += bf2f((unsigned short)(u & 0xffffu));
      hi += bf2f((unsigned short)(u >> 16));
    }
    lo += __shfl_xor(lo, 1);
    hi += __shfl_xor(hi, 1);
    if (half == 0) {
      const int pr = e >> 7, col = e & 127;
      G[(2 * pr) * 128 + col]     = lo;
      G[(2 * pr + 1) * 128 + col] = hi;
    }
  } else {
    if (tid < 128) {
      float s = 0.f;
      #pragma unroll 8
      for (int p = 0; p < 256; ++p) s += svpart[p * 128 + tid];
      sv[tid] = s;
    }
  }
}

// ---------------------------------------------------------------------------
// K3: BN parameters from Gram matrix. grid 128 x 256.
// ---------------------------------------------------------------------------
__global__ __launch_bounds__(256) void k_params(
    const float* __restrict__ G, const float* __restrict__ sv,
    const float* __restrict__ W1, const float* __restrict__ gamma,
    const float* __restrict__ beta, float* __restrict__ scale,
    float* __restrict__ shiftv)
{
  __shared__ float Gl[128][133];
  __shared__ float Wl[128][16];
  __shared__ float redq[16][16];
  __shared__ float redm[16][16];
  const int tid = threadIdx.x;
  const int jb = blockIdx.x * 16;
  for (int i = tid; i < 16384; i += 256) Gl[i >> 7][i & 127] = G[i];
  for (int i = tid; i < 2048; i += 256) {
    int k = i >> 4, col = i & 15;
    Wl[k][col] = W1[(size_t)k * 2048 + jb + col];
  }
  __syncthreads();
  const int col = tid & 15, part = tid >> 4;
  float msq = 0.f, mean = 0.f;
  for (int ii = 0; ii < 8; ++ii) {
    const int i = part * 8 + ii;
    const float wi = Wl[i][col];
    float inner = 0.f;
    #pragma unroll 8
    for (int k = 0; k < 128; ++k) inner = fmaf(Gl[i][k], Wl[k][col], inner);
    msq = fmaf(wi, inner, msq);
  }
  #pragma unroll
  for (int kk = 0; kk < 8; ++kk) {
    const int k = part * 8 + kk;
    mean = fmaf(sv[k], Wl[k][col], mean);
  }
  redq[part][col] = msq;
  redm[part][col] = mean;
  __syncthreads();
  if (tid < 16) {
    float q = 0.f, m = 0.f;
    #pragma unroll
    for (int p = 0; p < 16; ++p) { q += redq[p][tid]; m += redm[p][tid]; }
    m *= (1.f / 65536.f);
    q *= (1.f / 65536.f);
    float var = q - m * m;
    float sc = gamma[jb + tid] * rsqrtf(var + 1e-5f);
    scale[jb + tid] = sc;
    shiftv[jb + tid] = beta[jb + tid] - m * sc;
  }
}

// ---------------------------------------------------------------------------
// K4: fused main. 512 blocks x 512 thr (8 waves); block = 128 consecutive rows.
// LDS counting-sort rows by category -> ~16 MFMA groups of <=16 rows; groups
// round-robin over waves. Output accumulated in LDS obuf (block-private,
// line-aligned region) then dumped fully coalesced. No scatter/tmp/permute.
// ---------------------------------------------------------------------------
__global__ __launch_bounds__(512, 4) void k_main(
    const float* __restrict__ F, const unsigned short* __restrict__ Wlb,
    const float* __restrict__ W2, const float* __restrict__ bias,
    const float* __restrict__ scale, const float* __restrict__ shiftv,
    const int* __restrict__ lab, float* __restrict__ out)
{
  __shared__ float W2l[16 * 784];        // padded: idx = cat*784 + c*6 + s + (c>>3)
  __shared__ float obuf[128 * 54];       // block's output rows
  __shared__ unsigned short lrows[128];  // slot -> local row
  __shared__ int wcs[2][NCAT];
  __shared__ int loff[NCAT + 1];
  __shared__ unsigned char gcat[32], gsub[32];
  __shared__ int gtot;

  const int tid = threadIdx.x;
  const int blk = (int)blockIdx.x;
  const int wid = tid >> 6, lane = tid & 63;
  const int lrow = lane & 15, lhi = lane >> 4;

  // stage W2 (padded) + zero obuf
  for (int i = tid; i < 12288; i += 512) {
    const int cat = i / 768;
    const int r = i - cat * 768;
    const int c = r / 6, s = r - c * 6;
    W2l[cat * 784 + c * 6 + s + (c >> 3)] = W2[i];
  }
  for (int i = tid; i < 6912; i += 512) obuf[i] = 0.f;

  // per-wave ballot histogram + rank (rows live in waves 0,1)
  int myc = 0, myrank = 0;
  if (tid < 128) {
    myc = lab[blk * 128 + tid];
    const unsigned long long lanebit = 1ull << lane;
    #pragma unroll
    for (int cc = 0; cc < NCAT; ++cc) {
      unsigned long long m = __ballot(myc == cc);
      if (lane == 0) wcs[wid][cc] = (int)__popcll(m);
      if (myc == cc) myrank = (int)__popcll(m & (lanebit - 1));
    }
  }
  __syncthreads();
  if (tid == 0) {
    int a = 0, g = 0;
    for (int c = 0; c < NCAT; ++c) {
      loff[c] = a;
      const int cnt = wcs[0][c] + wcs[1][c];
      for (int s2 = 0; s2 * 16 < cnt; ++s2) {
        gcat[g] = (unsigned char)c; gsub[g] = (unsigned char)s2; ++g;
      }
      a += cnt;
    }
    loff[NCAT] = a;
    gtot = g;
  }
  __syncthreads();
  if (tid < 128) {
    const int slot = loff[myc] + ((tid >= 64) ? wcs[0][myc] : 0) + myrank;
    lrows[slot] = (unsigned short)tid;
  }
  __syncthreads();

  float bi[6];
  #pragma unroll
  for (int s = 0; s < 6; ++s) bi[s] = bias[s];

  const int ng = gtot;
  for (int g = wid; g < ng; g += 8) {
    const int cat = gcat[g];
    const int slot0 = loff[cat] + ((int)gsub[g] << 4);
    const int hi2 = loff[cat + 1];
    const int navail = min(16, hi2 - slot0);
    const int srow = lrows[min(slot0 + lrow, hi2 - 1)];   // clamped (dup rows padded)
    const float* fp = F + ((size_t)(blk * 128 + srow)) * 128 + lhi * 8;
    const unsigned short* wbase = Wlb + (size_t)cat * 16384;

    float4v acc[8];
    #pragma unroll
    for (int ct = 0; ct < 8; ++ct) acc[ct] = (float4v){0.f, 0.f, 0.f, 0.f};

    #pragma unroll
    for (int ks = 0; ks < 4; ++ks) {
      const float4 a0 = *(const float4*)(fp + ks * 32);
      const float4 a1 = *(const float4*)(fp + ks * 32 + 4);
      uint4 av4;
      av4.x = pk2(a0.x, a0.y); av4.y = pk2(a0.z, a0.w);
      av4.z = pk2(a1.x, a1.y); av4.w = pk2(a1.z, a1.w);
      const short8v av = __builtin_bit_cast(short8v, av4);
      #pragma unroll
      for (int ct = 0; ct < 8; ++ct) {
        short8v bv = *(const short8v*)(wbase + ((ks * 8 + ct) * 64 + lane) * 8);
        acc[ct] = __builtin_amdgcn_mfma_f32_16x16x32_bf16(av, bv, acc[ct], 0, 0, 0);
      }
    }

    // BN + leaky + W2 partials (lane col c = 16ct+lrow; rows 4*lhi+j)
    float p[4][6];
    #pragma unroll
    for (int j = 0; j < 4; ++j)
      #pragma unroll
      for (int s = 0; s < 6; ++s) p[j][s] = 0.f;
    #pragma unroll
    for (int ct = 0; ct < 8; ++ct) {
      const int c = ct * 16 + lrow;
      const float s_ = scale[cat * 128 + c];
      const float h_ = shiftv[cat * 128 + c];
      float w2v[6];
      #pragma unroll
      for (int s = 0; s < 6; ++s) w2v[s] = W2l[cat * 784 + c * 6 + s + (c >> 3)];
      #pragma unroll
      for (int j = 0; j < 4; ++j) {
        float a = acc[ct][j] * s_ + h_;
        a = (a >= 0.f) ? a : 0.2f * a;
        #pragma unroll
        for (int s = 0; s < 6; ++s) p[j][s] = fmaf(a, w2v[s], p[j][s]);
      }
    }
    // reduce-scatter over the 16-lane group (channels): lvl1/2 keep j == lrow&3
    const bool b1 = (lrow & 1) != 0;
    const bool b2 = (lrow & 2) != 0;
    float q[2][6], r[6];
    #pragma unroll
    for (int t = 0; t < 2; ++t)
      #pragma unroll
      for (int s = 0; s < 6; ++s) {
        float snd = b1 ? p[2 * t][s] : p[2 * t + 1][s];
        float kp  = b1 ? p[2 * t + 1][s] : p[2 * t][s];
        q[t][s] = kp + __shfl_xor(snd, 1);
      }
    #pragma unroll
    for (int s = 0; s < 6; ++s) {
      float snd = b2 ? q[0][s] : q[1][s];
      float kp  = b2 ? q[1][s] : q[0][s];
      r[s] = kp + __shfl_xor(snd, 2);
    }
    #pragma unroll
    for (int s = 0; s < 6; ++s) r[s] += __shfl_xor(r[s], 4);
    #pragma unroll
    for (int s = 0; s < 6; ++s) r[s] += __shfl_xor(r[s], 8);

    const int jj = lrow & 3, sb = lrow >> 2;
    const int jrow = 4 * lhi + jj;
    float pj[6];
    #pragma unroll
    for (int s = 0; s < 6; ++s) pj[s] = r[s] + bi[s];
    float mx = fmaxf(fmaxf(fmaxf(pj[0], pj[1]), fmaxf(pj[2], pj[3])), fmaxf(pj[4], pj[5]));
    float e = __expf(pj[0] - mx) + __expf(pj[1] - mx) + __expf(pj[2] - mx)
            + __expf(pj[3] - mx) + __expf(pj[4] - mx) + __expf(pj[5] - mx);
    float lse = mx + __logf(e);

    if (jrow < navail) {
      const int orow = (int)lrows[slot0 + jrow];
      const int shc = c_shift[cat], lnc = c_len[cat];
      float* ob = obuf + orow * 54 + shc;
      if (sb == 0) {
        ob[0] = pj[0] - lse;
        ob[1] = pj[1] - lse;                 // lnc >= 2 always
        if (lnc > 2) ob[2] = pj[2] - lse;
        if (lnc > 3) ob[3] = pj[3] - lse;
      } else if (sb == 1) {
        if (lnc > 4) ob[4] = pj[4] - lse;
        if (lnc > 5) ob[5] = pj[5] - lse;
      }
    }
  }
  __syncthreads();

  // coalesced dump: block-private, line-aligned 27648-B region
  const float2* ob2 = (const float2*)obuf;
  float2* o2 = (float2*)(out + (size_t)blk * 6912);
  for (int i = tid; i < 3456; i += 512) o2[i] = ob2[i];
}

// ---------------------------------------------------------------------------
// Host launcher — 4 launches (fast path), 3 graph boundaries.
// ---------------------------------------------------------------------------
extern "C" void kernel_launch(void* const* d_in, const int* in_sizes, int n_in,
                              void* d_out, int out_size, void* d_ws, size_t ws_size,
                              hipStream_t stream) {
  const float* F     = (const float*)d_in[0];
  const float* W1    = (const float*)d_in[1];
  const float* gamma = (const float*)d_in[2];
  const float* beta  = (const float*)d_in[3];
  const float* W2    = (const float*)d_in[4];
  const float* bias  = (const float*)d_in[5];
  const int*   lab   = (const int*)d_in[6];
  float* out = (float*)d_out;

  char* ws = (char*)d_ws;
  float* scale   = (float*)(ws + 0);
  float* shiftv  = (float*)(ws + 8192);
  float* G       = (float*)(ws + 16384);
  float* sv      = (float*)(ws + 81920);
  unsigned short* Wlb = (unsigned short*)(ws + 82432);
  unsigned* Gp16 = (unsigned*)(ws + 606720);
  float* svpart  = (float*)(ws + 8995328);

  const size_t need = 9126400;
  if (ws_size >= need) {
    hipLaunchKernelGGL(k_stats_m<true>, dim3(272), dim3(1024), 0, stream,
                       F, W1, G, Gp16, sv, svpart, Wlb);
    hipLaunchKernelGGL(k_reduce, dim3(65), dim3(256), 0, stream,
                       Gp16, svpart, G, sv);
  } else {
    hipMemsetAsync(ws + 16384, 0, 66048, stream);   // G + sv for atomic path
    hipLaunchKernelGGL(k_stats_m<false>, dim3(272), dim3(1024), 0, stream,
                       F, W1, G, Gp16, sv, svpart, Wlb);
  }
  hipLaunchKernelGGL(k_params, dim3(128), dim3(256), 0, stream,
                     G, sv, W1, gamma, beta, scale, shiftv);
  hipLaunchKernelGGL(k_main, dim3(512), dim3(512), 0, stream,
                     F, Wlb, W2, bias, scale, shiftv, lab, out);
}